// Round 1
// baseline (285.048 us; speedup 1.0000x reference)
//
#include <hip/hip_runtime.h>

#define B_ 2
#define S_ 2048
#define H_ 1024
#define NH_ 16
#define HD_ 64

typedef short s16x8 __attribute__((ext_vector_type(8)));
typedef float f32x4 __attribute__((ext_vector_type(4)));

// float -> bf16 round-to-nearest-even (no NaN inputs here)
__device__ __forceinline__ ushort f2bf(float f) {
  union { float f; unsigned u; } v;
  v.f = f;
  unsigned r = (v.u + 0x7fffu + ((v.u >> 16) & 1u)) >> 16;
  return (ushort)r;
}

// async global->LDS, 16B per lane (dest must be wave-uniform base + lane*16)
__device__ __forceinline__ void gload16(const void* g, void* l) {
  typedef const __attribute__((address_space(1))) unsigned int* gp_t;
  typedef __attribute__((address_space(3))) unsigned int* lp_t;
  __builtin_amdgcn_global_load_lds((gp_t)g, (lp_t)l, 16, 0, 0);
}

// ---------------- fp32 -> bf16 elementwise (x) ----------------
__global__ __launch_bounds__(256) void k_convert(const float* __restrict__ in,
                                                 ushort* __restrict__ out) {
  int i = blockIdx.x * 256 + threadIdx.x;  // grid covers exactly n/4 float4s
  float4 v = ((const float4*)in)[i];
  ushort4 o;
  o.x = f2bf(v.x); o.y = f2bf(v.y); o.z = f2bf(v.z); o.w = f2bf(v.w);
  ((ushort4*)out)[i] = o;
}

// ------------- transpose + convert: f32 [R][C] -> bf16 [C][R] -------------
__global__ __launch_bounds__(256) void k_transpose(const float* __restrict__ in,
                                                   ushort* __restrict__ out,
                                                   int R, int C) {
  __shared__ ushort tile[32][33];
  int c0 = blockIdx.x * 32, r0 = blockIdx.y * 32;
  int tr = threadIdx.x >> 5, tc = threadIdx.x & 31;
#pragma unroll
  for (int i = 0; i < 4; ++i)
    tile[tr + 8 * i][tc] = f2bf(in[(size_t)(r0 + tr + 8 * i) * C + c0 + tc]);
  __syncthreads();
#pragma unroll
  for (int i = 0; i < 4; ++i)
    out[(size_t)(c0 + tr + 8 * i) * R + r0 + tc] = tile[tc][tr + 8 * i];
}

// ---------------- GEMM: C[M][N] = A[M][K] * Bt[N][K]^T (bf16 in, f32 acc) ----
// MODE 0: QKV epilogue -> Q,K row-major bf16; V transposed per (b,h): Vt[(b*16+h)*64+d][s]
// MODE 1: fp32 row-major out
template <int MODE>
__global__ __launch_bounds__(256) void k_gemm(const ushort* __restrict__ A,
                                              const ushort* __restrict__ Bt,
                                              void* __restrict__ out0,
                                              ushort* __restrict__ outK,
                                              ushort* __restrict__ outV,
                                              int Kdim, int Ndim) {
  __shared__ __align__(16) ushort As[128 * 64];
  __shared__ __align__(16) ushort Bs[128 * 64];
  const int m0 = blockIdx.y * 128, n0 = blockIdx.x * 128;
  const int tid = threadIdx.x, lane = tid & 63, w = tid >> 6;
  const int g = lane >> 4, c = lane & 15;
  const int wr = w >> 1, wc = w & 1;
  f32x4 acc[4][4] = {};
  const int trow = tid >> 3, tcol = tid & 7;
  const ushort* ag = A + (size_t)(m0 + trow) * Kdim + tcol * 8;
  const ushort* bg = Bt + (size_t)(n0 + trow) * Kdim + tcol * 8;
  ushort* la = As + tid * 8;
  ushort* lb = Bs + tid * 8;

  for (int k0 = 0; k0 < Kdim; k0 += 64) {
#pragma unroll
    for (int i = 0; i < 4; ++i) {
      gload16(ag + k0 + i * 32 * Kdim, la + i * 2048);
      gload16(bg + k0 + i * 32 * Kdim, lb + i * 2048);
    }
    __syncthreads();
#pragma unroll
    for (int kk = 0; kk < 64; kk += 32) {
      s16x8 af[4], bfr[4];
#pragma unroll
      for (int i = 0; i < 4; ++i)
        af[i] = *(const s16x8*)(As + (wr * 64 + i * 16 + c) * 64 + kk + g * 8);
#pragma unroll
      for (int i = 0; i < 4; ++i)
        bfr[i] = *(const s16x8*)(Bs + (wc * 64 + i * 16 + c) * 64 + kk + g * 8);
#pragma unroll
      for (int i = 0; i < 4; ++i)
#pragma unroll
        for (int j = 0; j < 4; ++j)
          acc[i][j] = __builtin_amdgcn_mfma_f32_16x16x32_bf16(af[i], bfr[j], acc[i][j], 0, 0, 0);
    }
    __syncthreads();
  }

  if (MODE == 1) {
    float* out = (float*)out0;
#pragma unroll
    for (int i = 0; i < 4; ++i) {
      int mb = m0 + wr * 64 + i * 16 + g * 4;
#pragma unroll
      for (int j = 0; j < 4; ++j) {
        int n = n0 + wc * 64 + j * 16 + c;
#pragma unroll
        for (int r = 0; r < 4; ++r)
          out[(size_t)(mb + r) * Ndim + n] = acc[i][j][r];
      }
    }
  } else {
    if (n0 < 1024) {               // Q part
      ushort* outQ = (ushort*)out0;
#pragma unroll
      for (int i = 0; i < 4; ++i) {
        int mb = m0 + wr * 64 + i * 16 + g * 4;
#pragma unroll
        for (int j = 0; j < 4; ++j) {
          int n = n0 + wc * 64 + j * 16 + c;
#pragma unroll
          for (int r = 0; r < 4; ++r)
            outQ[(size_t)(mb + r) * 1024 + n] = f2bf(acc[i][j][r]);
        }
      }
    } else if (n0 < 2048) {        // K part
#pragma unroll
      for (int i = 0; i < 4; ++i) {
        int mb = m0 + wr * 64 + i * 16 + g * 4;
#pragma unroll
        for (int j = 0; j < 4; ++j) {
          int n = n0 - 1024 + wc * 64 + j * 16 + c;
#pragma unroll
          for (int r = 0; r < 4; ++r)
            outK[(size_t)(mb + r) * 1024 + n] = f2bf(acc[i][j][r]);
        }
      }
    } else {                       // V part: write transposed per (b,h): Vt[.][s]
#pragma unroll
      for (int i = 0; i < 4; ++i) {
        int mb = m0 + wr * 64 + i * 16 + g * 4;
        int bidx = mb >> 11;       // which batch (tile never crosses the 2048 row boundary)
        int s = mb & 2047;
#pragma unroll
        for (int j = 0; j < 4; ++j) {
          int nv = n0 - 2048 + wc * 64 + j * 16 + c;
          int h = nv >> 6, d = nv & 63;
          ushort4 pk;
          pk.x = f2bf(acc[i][j][0]);
          pk.y = f2bf(acc[i][j][1]);
          pk.z = f2bf(acc[i][j][2]);
          pk.w = f2bf(acc[i][j][3]);
          *(ushort4*)(outV + ((size_t)((bidx * 16 + h) * 64 + d)) * 2048 + s) = pk;
        }
      }
    }
  }
}

// ---------------- flash causal attention ----------------
// grid: (S/128, B*NH). 4 waves/block, each wave owns 32 q rows. KVBLK=64.
// K staged [64 k][64 d], V staged from Vt as [64 d][64 k]; both XOR-swizzled
// (16B chunk c stored at c^(row&7)) via pre-swizzled global source (T2/m231 rule).
__global__ __launch_bounds__(256) void k_attn(const ushort* __restrict__ Qb,
                                              const ushort* __restrict__ Kb,
                                              const ushort* __restrict__ Vt,
                                              ushort* __restrict__ Yb) {
  __shared__ __align__(16) ushort Ks[64 * 64];
  __shared__ __align__(16) ushort Vs[64 * 64];
  __shared__ __align__(16) ushort Ps[4 * 32 * 64];
  const int qt0 = blockIdx.x * 128;
  const int bh = blockIdx.y, b = bh >> 4, h = bh & 15;
  const int tid = threadIdx.x, w = tid >> 6, lane = tid & 63;
  const int g = lane >> 4, c = lane & 15;
  const int qw = qt0 + w * 32;  // wave's first q row

  // Q fragments held in registers for the whole block
  s16x8 qf[2][2];
#pragma unroll
  for (int qt = 0; qt < 2; ++qt)
#pragma unroll
    for (int dc = 0; dc < 2; ++dc)
      qf[qt][dc] = *(const s16x8*)(Qb + (size_t)(b * S_ + qw + qt * 16 + c) * H_ +
                                   h * HD_ + dc * 32 + g * 8);

  f32x4 oacc[2][4] = {};
  float mrow[2][4], lrow[2][4];
#pragma unroll
  for (int qt = 0; qt < 2; ++qt)
#pragma unroll
    for (int r = 0; r < 4; ++r) { mrow[qt][r] = -1e30f; lrow[qt][r] = 0.f; }

  const int trow = tid >> 3, tcol = tid & 7;
  const int csrc = tcol ^ (trow & 7);  // inverse-swizzled global source chunk
  const ushort* kg = Kb + (size_t)(b * S_ + trow) * H_ + h * HD_ + csrc * 8;
  const ushort* vg = Vt + (size_t)((b * NH_ + h) * HD_ + trow) * S_ + csrc * 8;

  const int nt = (qt0 >> 6) + 2;  // causal: only tiles up to the diagonal
  for (int it = 0; it < nt; ++it) {
    const int ks = it * 64;
    gload16(kg + (size_t)ks * H_, Ks + tid * 8);
    gload16(kg + (size_t)(ks + 32) * H_, Ks + 2048 + tid * 8);
    gload16(vg + ks, Vs + tid * 8);
    gload16(vg + ks + 32 * S_, Vs + 2048 + tid * 8);
    __syncthreads();

    if (ks <= qw + 31) {  // wave has at least one unmasked row in this tile
      // ---- S = Q K^T ----
      f32x4 sacc[2][4] = {};
#pragma unroll
      for (int dc = 0; dc < 2; ++dc) {
#pragma unroll
        for (int kt = 0; kt < 4; ++kt) {
          int R = kt * 16 + c;
          int cc = dc * 4 + g;
          s16x8 kf = *(const s16x8*)((const char*)Ks + R * 128 + ((cc ^ (R & 7)) << 4));
#pragma unroll
          for (int qt = 0; qt < 2; ++qt)
            sacc[qt][kt] = __builtin_amdgcn_mfma_f32_16x16x32_bf16(qf[qt][dc], kf, sacc[qt][kt], 0, 0, 0);
        }
      }
      // ---- scale + causal mask ----
      const bool needmask = (ks + 63 > qw);
#pragma unroll
      for (int qt = 0; qt < 2; ++qt)
#pragma unroll
        for (int kt = 0; kt < 4; ++kt)
#pragma unroll
          for (int r = 0; r < 4; ++r) {
            float v = sacc[qt][kt][r] * 0.125f;  // 1/sqrt(64)
            if (needmask) {
              int kglob = ks + kt * 16 + c;
              int qglob = qw + qt * 16 + g * 4 + r;
              if (kglob > qglob) v = -1e30f;
            }
            sacc[qt][kt][r] = v;
          }
      // ---- online softmax: row max, rescale ----
#pragma unroll
      for (int qt = 0; qt < 2; ++qt)
#pragma unroll
        for (int r = 0; r < 4; ++r) {
          float t = fmaxf(fmaxf(sacc[qt][0][r], sacc[qt][1][r]),
                          fmaxf(sacc[qt][2][r], sacc[qt][3][r]));
          t = fmaxf(t, __shfl_xor(t, 1));
          t = fmaxf(t, __shfl_xor(t, 2));
          t = fmaxf(t, __shfl_xor(t, 4));
          t = fmaxf(t, __shfl_xor(t, 8));
          float mnew = fmaxf(mrow[qt][r], t);
          float sc = __expf(mrow[qt][r] - mnew);
          mrow[qt][r] = mnew;
          lrow[qt][r] *= sc;
#pragma unroll
          for (int dt = 0; dt < 4; ++dt) oacc[qt][dt][r] *= sc;
        }
      // ---- P = exp(S-m), write swizzled to LDS, accumulate row sums ----
      float rs[2][4] = {};
#pragma unroll
      for (int qt = 0; qt < 2; ++qt)
#pragma unroll
        for (int kt = 0; kt < 4; ++kt) {
          int chw = kt * 2 + (c >> 3);
#pragma unroll
          for (int r = 0; r < 4; ++r) {
            float p = __expf(sacc[qt][kt][r] - mrow[qt][r]);
            rs[qt][r] += p;
            int row = w * 32 + qt * 16 + g * 4 + r;
            *(ushort*)((char*)Ps + row * 128 + ((chw ^ (row & 7)) << 4) + ((c & 7) << 1)) = f2bf(p);
          }
        }
#pragma unroll
      for (int qt = 0; qt < 2; ++qt)
#pragma unroll
        for (int r = 0; r < 4; ++r) {
          float t = rs[qt][r];
          t += __shfl_xor(t, 1);
          t += __shfl_xor(t, 2);
          t += __shfl_xor(t, 4);
          t += __shfl_xor(t, 8);
          lrow[qt][r] += t;
        }
      // wave-local LDS write->read ordering (single wave, no block barrier needed)
      asm volatile("s_waitcnt lgkmcnt(0)" ::: "memory");
      __builtin_amdgcn_sched_barrier(0);
      // ---- O += P V ----
#pragma unroll
      for (int kc = 0; kc < 2; ++kc) {
        s16x8 pf[2];
#pragma unroll
        for (int qt = 0; qt < 2; ++qt) {
          int qr = qt * 16 + c;
          int row = w * 32 + qr;
          int cc = kc * 4 + g;
          pf[qt] = *(const s16x8*)((const char*)Ps + row * 128 + ((cc ^ (qr & 7)) << 4));
        }
#pragma unroll
        for (int dt = 0; dt < 4; ++dt) {
          int R = dt * 16 + c;
          int cc = kc * 4 + g;
          s16x8 vf = *(const s16x8*)((const char*)Vs + R * 128 + ((cc ^ (R & 7)) << 4));
#pragma unroll
          for (int qt = 0; qt < 2; ++qt)
            oacc[qt][dt] = __builtin_amdgcn_mfma_f32_16x16x32_bf16(pf[qt], vf, oacc[qt][dt], 0, 0, 0);
        }
      }
    }
    __syncthreads();
  }

  // ---- epilogue: O / l -> Yb (bf16) ----
#pragma unroll
  for (int qt = 0; qt < 2; ++qt)
#pragma unroll
    for (int dt = 0; dt < 4; ++dt)
#pragma unroll
      for (int r = 0; r < 4; ++r) {
        int s = qw + qt * 16 + g * 4 + r;
        float v = oacc[qt][dt][r] / lrow[qt][r];
        Yb[(size_t)(b * S_ + s) * H_ + h * HD_ + dt * 16 + c] = f2bf(v);
      }
}

extern "C" void kernel_launch(void* const* d_in, const int* in_sizes, int n_in,
                              void* d_out, int out_size, void* d_ws, size_t ws_size,
                              hipStream_t stream) {
  (void)in_sizes; (void)n_in; (void)out_size; (void)ws_size;
  const float* x = (const float*)d_in[0];
  // d_in[1] is the additive causal mask -- causality implemented directly.
  const float* Wqkv = (const float*)d_in[2];
  const float* Wout = (const float*)d_in[3];
  float* out = (float*)d_out;

  char* ws = (char*)d_ws;
  ushort* xb    = (ushort*)(ws + 0);          //  8 MB  x as bf16 [4096][1024]
  ushort* wqkvT = (ushort*)(ws + 8388608);    //  6 MB  W_qkv^T bf16 [3072][1024]
  ushort* woutT = (ushort*)(ws + 14680064);   //  2 MB  W_out^T bf16 [1024][1024]
  ushort* Qb    = (ushort*)(ws + 16777216);   //  8 MB  Q bf16 [B*S][H]
  ushort* Kb    = (ushort*)(ws + 25165824);   //  8 MB  K bf16 [B*S][H]
  ushort* Vtb   = (ushort*)(ws + 33554432);   //  8 MB  V^T bf16 [B*NH*HD][S]
  ushort* Yb    = (ushort*)(ws + 41943040);   //  8 MB  attn out bf16 [B*S][H]

  k_convert<<<dim3(4096), dim3(256), 0, stream>>>(x, xb);
  k_transpose<<<dim3(96, 32), dim3(256), 0, stream>>>(Wqkv, wqkvT, 1024, 3072);
  k_transpose<<<dim3(32, 32), dim3(256), 0, stream>>>(Wout, woutT, 1024, 1024);
  k_gemm<0><<<dim3(24, 32), dim3(256), 0, stream>>>(xb, wqkvT, (void*)Qb, Kb, Vtb, 1024, 3072);
  k_attn<<<dim3(16, 32), dim3(256), 0, stream>>>(Qb, Kb, Vtb, Yb);
  k_gemm<1><<<dim3(8, 32), dim3(256), 0, stream>>>(Yb, woutT, (void*)out, nullptr, nullptr, 1024, 1024);
}

// Round 2
// 242.521 us; speedup vs baseline: 1.1754x; 1.1754x over previous
//
#include <hip/hip_runtime.h>

#define B_ 2
#define S_ 2048
#define H_ 1024
#define NH_ 16
#define HD_ 64

typedef short s16x8 __attribute__((ext_vector_type(8)));
typedef float f32x4 __attribute__((ext_vector_type(4)));

// float -> bf16 round-to-nearest-even (no NaN inputs here)
__device__ __forceinline__ ushort f2bf(float f) {
  union { float f; unsigned u; } v;
  v.f = f;
  unsigned r = (v.u + 0x7fffu + ((v.u >> 16) & 1u)) >> 16;
  return (ushort)r;
}

// async global->LDS, 16B per lane (dest must be wave-uniform base + lane*16)
__device__ __forceinline__ void gload16(const void* g, void* l) {
  typedef const __attribute__((address_space(1))) unsigned int* gp_t;
  typedef __attribute__((address_space(3))) unsigned int* lp_t;
  __builtin_amdgcn_global_load_lds((gp_t)g, (lp_t)l, 16, 0, 0);
}

// ---------------- fp32 -> bf16 elementwise (x) ----------------
__global__ __launch_bounds__(256) void k_convert(const float* __restrict__ in,
                                                 ushort* __restrict__ out) {
  int i = blockIdx.x * 256 + threadIdx.x;  // grid covers exactly n/4 float4s
  float4 v = ((const float4*)in)[i];
  ushort4 o;
  o.x = f2bf(v.x); o.y = f2bf(v.y); o.z = f2bf(v.z); o.w = f2bf(v.w);
  ((ushort4*)out)[i] = o;
}

// ------------- transpose + convert: f32 [R][C] -> bf16 [C][R] -------------
__global__ __launch_bounds__(256) void k_transpose(const float* __restrict__ in,
                                                   ushort* __restrict__ out,
                                                   int R, int C) {
  __shared__ ushort tile[32][33];
  int c0 = blockIdx.x * 32, r0 = blockIdx.y * 32;
  int tr = threadIdx.x >> 5, tc = threadIdx.x & 31;
#pragma unroll
  for (int i = 0; i < 4; ++i)
    tile[tr + 8 * i][tc] = f2bf(in[(size_t)(r0 + tr + 8 * i) * C + c0 + tc]);
  __syncthreads();
#pragma unroll
  for (int i = 0; i < 4; ++i)
    out[(size_t)(c0 + tr + 8 * i) * R + r0 + tc] = tile[tc][tr + 8 * i];
}

// ---------------- GEMM: C[M][N] = A[M][K] * Bt[N][K]^T (bf16 in, f32 acc) ----
// MODE 0: QKV epilogue -> Q,K row-major bf16; V transposed per (b,h): Vt[(b*16+h)*64+d][s]
// MODE 1: fp32 row-major out
template <int MODE>
__global__ __launch_bounds__(256) void k_gemm(const ushort* __restrict__ A,
                                              const ushort* __restrict__ Bt,
                                              void* __restrict__ out0,
                                              ushort* __restrict__ outK,
                                              ushort* __restrict__ outV,
                                              int Kdim, int Ndim) {
  __shared__ __align__(16) ushort As[128 * 64];
  __shared__ __align__(16) ushort Bs[128 * 64];
  const int m0 = blockIdx.y * 128, n0 = blockIdx.x * 128;
  const int tid = threadIdx.x, lane = tid & 63, w = tid >> 6;
  const int g = lane >> 4, c = lane & 15;
  const int wr = w >> 1, wc = w & 1;
  f32x4 acc[4][4] = {};
  const int trow = tid >> 3, tcol = tid & 7;
  const ushort* ag = A + (size_t)(m0 + trow) * Kdim + tcol * 8;
  const ushort* bg = Bt + (size_t)(n0 + trow) * Kdim + tcol * 8;
  ushort* la = As + tid * 8;
  ushort* lb = Bs + tid * 8;

  for (int k0 = 0; k0 < Kdim; k0 += 64) {
#pragma unroll
    for (int i = 0; i < 4; ++i) {
      gload16(ag + k0 + i * 32 * Kdim, la + i * 2048);
      gload16(bg + k0 + i * 32 * Kdim, lb + i * 2048);
    }
    __syncthreads();
#pragma unroll
    for (int kk = 0; kk < 64; kk += 32) {
      s16x8 af[4], bfr[4];
#pragma unroll
      for (int i = 0; i < 4; ++i)
        af[i] = *(const s16x8*)(As + (wr * 64 + i * 16 + c) * 64 + kk + g * 8);
#pragma unroll
      for (int i = 0; i < 4; ++i)
        bfr[i] = *(const s16x8*)(Bs + (wc * 64 + i * 16 + c) * 64 + kk + g * 8);
#pragma unroll
      for (int i = 0; i < 4; ++i)
#pragma unroll
        for (int j = 0; j < 4; ++j)
          acc[i][j] = __builtin_amdgcn_mfma_f32_16x16x32_bf16(af[i], bfr[j], acc[i][j], 0, 0, 0);
    }
    __syncthreads();
  }

  if (MODE == 1) {
    float* out = (float*)out0;
#pragma unroll
    for (int i = 0; i < 4; ++i) {
      int mb = m0 + wr * 64 + i * 16 + g * 4;
#pragma unroll
      for (int j = 0; j < 4; ++j) {
        int n = n0 + wc * 64 + j * 16 + c;
#pragma unroll
        for (int r = 0; r < 4; ++r)
          out[(size_t)(mb + r) * Ndim + n] = acc[i][j][r];
      }
    }
  } else {
    if (n0 < 1024) {               // Q part
      ushort* outQ = (ushort*)out0;
#pragma unroll
      for (int i = 0; i < 4; ++i) {
        int mb = m0 + wr * 64 + i * 16 + g * 4;
#pragma unroll
        for (int j = 0; j < 4; ++j) {
          int n = n0 + wc * 64 + j * 16 + c;
#pragma unroll
          for (int r = 0; r < 4; ++r)
            outQ[(size_t)(mb + r) * 1024 + n] = f2bf(acc[i][j][r]);
        }
      }
    } else if (n0 < 2048) {        // K part
#pragma unroll
      for (int i = 0; i < 4; ++i) {
        int mb = m0 + wr * 64 + i * 16 + g * 4;
#pragma unroll
        for (int j = 0; j < 4; ++j) {
          int n = n0 - 1024 + wc * 64 + j * 16 + c;
#pragma unroll
          for (int r = 0; r < 4; ++r)
            outK[(size_t)(mb + r) * 1024 + n] = f2bf(acc[i][j][r]);
        }
      }
    } else {                       // V part: write transposed per (b,h): Vt[.][s]
#pragma unroll
      for (int i = 0; i < 4; ++i) {
        int mb = m0 + wr * 64 + i * 16 + g * 4;
        int bidx = mb >> 11;       // which batch (tile never crosses the 2048 row boundary)
        int s = mb & 2047;
#pragma unroll
        for (int j = 0; j < 4; ++j) {
          int nv = n0 - 2048 + wc * 64 + j * 16 + c;
          int h = nv >> 6, d = nv & 63;
          ushort4 pk;
          pk.x = f2bf(acc[i][j][0]);
          pk.y = f2bf(acc[i][j][1]);
          pk.z = f2bf(acc[i][j][2]);
          pk.w = f2bf(acc[i][j][3]);
          *(ushort4*)(outV + ((size_t)((bidx * 16 + h) * 64 + d)) * 2048 + s) = pk;
        }
      }
    }
  }
}

// ---------------- flash causal attention (balanced + 2-phase pipelined) ----
// Flat grid 512, XCD-remapped so each XCD owns 4 heads (K/V ~2MB fits its L2).
// Each block: 4 waves x 16 q-rows = 64 q-rows per chunk; processes chunk j and
// chunk 31-j sequentially -> exactly 33 KV-tile iterations per block (balanced).
// K/V double-buffered in LDS via global_load_lds with XOR-swizzled source;
// 2-phase pipeline: STAGE(next) || compute(cur); vmcnt(0); s_barrier.
__global__ __launch_bounds__(256) void k_attn(const ushort* __restrict__ Qb,
                                              const ushort* __restrict__ Kb,
                                              const ushort* __restrict__ Vt,
                                              ushort* __restrict__ Yb) {
  __shared__ __align__(16) ushort Ks[2][64 * 64];
  __shared__ __align__(16) ushort Vs[2][64 * 64];
  __shared__ __align__(16) ushort Ps[64 * 64];
  const int fid = blockIdx.x;
  const int wid = (fid & 7) * 64 + (fid >> 3);  // XCD-contiguous remap (512 = 8*64)
  const int bh = wid >> 4;                       // 0..31
  const int j = wid & 15;                        // pair index 0..15
  const int b = bh >> 4, h = bh & 15;
  const int tid = threadIdx.x, w = tid >> 6, lane = tid & 63;
  const int g = lane >> 4, c = lane & 15;

  const int trow = tid >> 3, tcol = tid & 7;
  const int csrc = tcol ^ (trow & 7);  // inverse-swizzled global source chunk
  const ushort* kgb = Kb + (size_t)(b * S_ + trow) * H_ + h * HD_ + csrc * 8;
  const ushort* vgb = Vt + (size_t)(bh * HD_ + trow) * S_ + csrc * 8;

#define STAGE(bf, tile)                                          \
  do {                                                           \
    int ks_ = (tile) * 64;                                       \
    gload16(kgb + (size_t)ks_ * H_, Ks[bf] + tid * 8);           \
    gload16(kgb + (size_t)(ks_ + 32) * H_, Ks[bf] + 2048 + tid * 8); \
    gload16(vgb + ks_, Vs[bf] + tid * 8);                        \
    gload16(vgb + ks_ + 32 * S_, Vs[bf] + 2048 + tid * 8);       \
  } while (0)

#pragma unroll 1
  for (int half = 0; half < 2; ++half) {
    const int qc = half ? (31 - j) : j;  // q-chunk index (64 rows each)
    const int q0 = qc * 64;
    const int nt = qc + 1;               // causal: KV tiles 0..qc
    const int qw = q0 + w * 16;          // wave's first q row

    // Q fragments in registers for the whole chunk
    s16x8 qf[2];
#pragma unroll
    for (int dc = 0; dc < 2; ++dc)
      qf[dc] = *(const s16x8*)(Qb + (size_t)(b * S_ + qw + c) * H_ +
                               h * HD_ + dc * 32 + g * 8);

    f32x4 oacc[4] = {};
    float mrow[4], lrow[4];
#pragma unroll
    for (int r = 0; r < 4; ++r) { mrow[r] = -1e30f; lrow[r] = 0.f; }

    // prologue: stage tile 0, drain, barrier
    STAGE(0, 0);
    asm volatile("s_waitcnt vmcnt(0)" ::: "memory");
    __builtin_amdgcn_s_barrier();
    __builtin_amdgcn_sched_barrier(0);

    int buf = 0;
#pragma unroll 1
    for (int it = 0; it < nt; ++it) {
      const int ks = it * 64;
      if (it + 1 < nt) STAGE(buf ^ 1, it + 1);  // prefetch flies under compute

      // ---- S = Q K^T ----
      f32x4 sacc[4] = {};
#pragma unroll
      for (int dc = 0; dc < 2; ++dc) {
#pragma unroll
        for (int kt = 0; kt < 4; ++kt) {
          int R = kt * 16 + c;
          int cc = dc * 4 + g;
          s16x8 kf = *(const s16x8*)((const char*)Ks[buf] + R * 128 + ((cc ^ (R & 7)) << 4));
          sacc[kt] = __builtin_amdgcn_mfma_f32_16x16x32_bf16(qf[dc], kf, sacc[kt], 0, 0, 0);
        }
      }
      // ---- scale + causal mask (only last tile touches the diagonal) ----
      const bool lastt = (it == nt - 1);
#pragma unroll
      for (int kt = 0; kt < 4; ++kt)
#pragma unroll
        for (int r = 0; r < 4; ++r) {
          float v = sacc[kt][r] * 0.125f;  // 1/sqrt(64)
          if (lastt) {
            int kglob = ks + kt * 16 + c;
            int qglob = qw + g * 4 + r;
            if (kglob > qglob) v = -1e30f;
          }
          sacc[kt][r] = v;
        }
      // ---- online softmax: row max, rescale ----
#pragma unroll
      for (int r = 0; r < 4; ++r) {
        float t = fmaxf(fmaxf(sacc[0][r], sacc[1][r]), fmaxf(sacc[2][r], sacc[3][r]));
        t = fmaxf(t, __shfl_xor(t, 1));
        t = fmaxf(t, __shfl_xor(t, 2));
        t = fmaxf(t, __shfl_xor(t, 4));
        t = fmaxf(t, __shfl_xor(t, 8));
        float mnew = fmaxf(mrow[r], t);
        float sc = __expf(mrow[r] - mnew);
        mrow[r] = mnew;
        lrow[r] *= sc;
#pragma unroll
        for (int dt = 0; dt < 4; ++dt) oacc[dt][r] *= sc;
      }
      // ---- P = exp(S-m), swizzled LDS write, row sums ----
      float rs[4] = {};
#pragma unroll
      for (int kt = 0; kt < 4; ++kt) {
        int chw = kt * 2 + (c >> 3);
#pragma unroll
        for (int r = 0; r < 4; ++r) {
          float p = __expf(sacc[kt][r] - mrow[r]);
          rs[r] += p;
          int row = w * 16 + g * 4 + r;
          *(ushort*)((char*)Ps + row * 128 + ((chw ^ (row & 7)) << 4) + ((c & 7) << 1)) = f2bf(p);
        }
      }
#pragma unroll
      for (int r = 0; r < 4; ++r) {
        float t = rs[r];
        t += __shfl_xor(t, 1);
        t += __shfl_xor(t, 2);
        t += __shfl_xor(t, 4);
        t += __shfl_xor(t, 8);
        lrow[r] += t;
      }
      // wave-local LDS write->read ordering (each wave reads only its own rows)
      asm volatile("s_waitcnt lgkmcnt(0)" ::: "memory");
      __builtin_amdgcn_sched_barrier(0);
      // ---- O += P V ----
#pragma unroll
      for (int kc = 0; kc < 2; ++kc) {
        int prow = w * 16 + c;
        int cc = kc * 4 + g;
        s16x8 pf = *(const s16x8*)((const char*)Ps + prow * 128 + ((cc ^ (c & 7)) << 4));
#pragma unroll
        for (int dt = 0; dt < 4; ++dt) {
          int R = dt * 16 + c;
          s16x8 vf = *(const s16x8*)((const char*)Vs[buf] + R * 128 + ((cc ^ (R & 7)) << 4));
          oacc[dt] = __builtin_amdgcn_mfma_f32_16x16x32_bf16(pf, vf, oacc[dt], 0, 0, 0);
        }
      }
      // ---- tile boundary: prefetched loads done; all waves done reading buf ----
      asm volatile("s_waitcnt vmcnt(0)" ::: "memory");
      __builtin_amdgcn_s_barrier();
      __builtin_amdgcn_sched_barrier(0);
      buf ^= 1;
    }

    // ---- epilogue: O / l -> Yb (bf16) ----
#pragma unroll
    for (int dt = 0; dt < 4; ++dt)
#pragma unroll
      for (int r = 0; r < 4; ++r) {
        int s = qw + g * 4 + r;
        float v = oacc[dt][r] / lrow[r];
        Yb[(size_t)(b * S_ + s) * H_ + h * HD_ + dt * 16 + c] = f2bf(v);
      }
  }
#undef STAGE
}

extern "C" void kernel_launch(void* const* d_in, const int* in_sizes, int n_in,
                              void* d_out, int out_size, void* d_ws, size_t ws_size,
                              hipStream_t stream) {
  (void)in_sizes; (void)n_in; (void)out_size; (void)ws_size;
  const float* x = (const float*)d_in[0];
  // d_in[1] is the additive causal mask -- causality implemented directly.
  const float* Wqkv = (const float*)d_in[2];
  const float* Wout = (const float*)d_in[3];
  float* out = (float*)d_out;

  char* ws = (char*)d_ws;
  ushort* xb    = (ushort*)(ws + 0);          //  8 MB  x as bf16 [4096][1024]
  ushort* wqkvT = (ushort*)(ws + 8388608);    //  6 MB  W_qkv^T bf16 [3072][1024]
  ushort* woutT = (ushort*)(ws + 14680064);   //  2 MB  W_out^T bf16 [1024][1024]
  ushort* Qb    = (ushort*)(ws + 16777216);   //  8 MB  Q bf16 [B*S][H]
  ushort* Kb    = (ushort*)(ws + 25165824);   //  8 MB  K bf16 [B*S][H]
  ushort* Vtb   = (ushort*)(ws + 33554432);   //  8 MB  V^T bf16 [B*NH*HD][S]
  ushort* Yb    = (ushort*)(ws + 41943040);   //  8 MB  attn out bf16 [B*S][H]

  k_convert<<<dim3(4096), dim3(256), 0, stream>>>(x, xb);
  k_transpose<<<dim3(96, 32), dim3(256), 0, stream>>>(Wqkv, wqkvT, 1024, 3072);
  k_transpose<<<dim3(32, 32), dim3(256), 0, stream>>>(Wout, woutT, 1024, 1024);
  k_gemm<0><<<dim3(24, 32), dim3(256), 0, stream>>>(xb, wqkvT, (void*)Qb, Kb, Vtb, 1024, 3072);
  k_attn<<<dim3(512), dim3(256), 0, stream>>>(Qb, Kb, Vtb, Yb);
  k_gemm<1><<<dim3(8, 32), dim3(256), 0, stream>>>(Yb, woutT, (void*)out, nullptr, nullptr, 1024, 1024);
}

// Round 3
// 216.051 us; speedup vs baseline: 1.3194x; 1.1225x over previous
//
#include <hip/hip_runtime.h>

#define B_ 2
#define S_ 2048
#define H_ 1024
#define NH_ 16
#define HD_ 64

typedef short s16x8 __attribute__((ext_vector_type(8)));
typedef float f32x4 __attribute__((ext_vector_type(4)));

// float -> bf16 round-to-nearest-even (no NaN inputs here)
__device__ __forceinline__ ushort f2bf(float f) {
  union { float f; unsigned u; } v;
  v.f = f;
  unsigned r = (v.u + 0x7fffu + ((v.u >> 16) & 1u)) >> 16;
  return (ushort)r;
}

// async global->LDS, 16B per lane (dest must be wave-uniform base + lane*16)
__device__ __forceinline__ void gload16(const void* g, void* l) {
  typedef const __attribute__((address_space(1))) unsigned int* gp_t;
  typedef __attribute__((address_space(3))) unsigned int* lp_t;
  __builtin_amdgcn_global_load_lds((gp_t)g, (lp_t)l, 16, 0, 0);
}

// ---------------- fp32 -> bf16 elementwise (x) ----------------
__global__ __launch_bounds__(256) void k_convert(const float* __restrict__ in,
                                                 ushort* __restrict__ out) {
  int i = blockIdx.x * 256 + threadIdx.x;  // grid covers exactly n/4 float4s
  float4 v = ((const float4*)in)[i];
  ushort4 o;
  o.x = f2bf(v.x); o.y = f2bf(v.y); o.z = f2bf(v.z); o.w = f2bf(v.w);
  ((ushort4*)out)[i] = o;
}

// ------------- transpose + convert: f32 [R][C] -> bf16 [C][R] -------------
__global__ __launch_bounds__(256) void k_transpose(const float* __restrict__ in,
                                                   ushort* __restrict__ out,
                                                   int R, int C) {
  __shared__ ushort tile[32][33];
  int c0 = blockIdx.x * 32, r0 = blockIdx.y * 32;
  int tr = threadIdx.x >> 5, tc = threadIdx.x & 31;
#pragma unroll
  for (int i = 0; i < 4; ++i)
    tile[tr + 8 * i][tc] = f2bf(in[(size_t)(r0 + tr + 8 * i) * C + c0 + tc]);
  __syncthreads();
#pragma unroll
  for (int i = 0; i < 4; ++i)
    out[(size_t)(c0 + tr + 8 * i) * R + r0 + tc] = tile[tc][tr + 8 * i];
}

// ---------------- GEMM: C[M][N] = A[M][K] * Bt[N][K]^T (bf16 in, f32 acc) ----
// MODE 0: QKV epilogue -> Q (pre-scaled by 0.125*log2e), K row-major bf16;
//         V transposed per (b,h): Vt[(b*16+h)*64+d][s]
// MODE 1: fp32 row-major out
template <int MODE>
__global__ __launch_bounds__(256) void k_gemm(const ushort* __restrict__ A,
                                              const ushort* __restrict__ Bt,
                                              void* __restrict__ out0,
                                              ushort* __restrict__ outK,
                                              ushort* __restrict__ outV,
                                              int Kdim, int Ndim) {
  __shared__ __align__(16) ushort As[128 * 64];
  __shared__ __align__(16) ushort Bs[128 * 64];
  // bijective XCD swizzle (grid % 8 == 0 for all our launches)
  const int nwg = gridDim.x * gridDim.y;
  const int id = blockIdx.y * gridDim.x + blockIdx.x;
  const int sid = (id & 7) * (nwg >> 3) + (id >> 3);
  const int m0 = (sid / gridDim.x) * 128, n0 = (sid % gridDim.x) * 128;
  const int tid = threadIdx.x, lane = tid & 63, w = tid >> 6;
  const int g = lane >> 4, c = lane & 15;
  const int wr = w >> 1, wc = w & 1;
  f32x4 acc[4][4] = {};
  const int trow = tid >> 3, tcol = tid & 7;
  const ushort* ag = A + (size_t)(m0 + trow) * Kdim + tcol * 8;
  const ushort* bg = Bt + (size_t)(n0 + trow) * Kdim + tcol * 8;
  ushort* la = As + tid * 8;
  ushort* lb = Bs + tid * 8;

  for (int k0 = 0; k0 < Kdim; k0 += 64) {
#pragma unroll
    for (int i = 0; i < 4; ++i) {
      gload16(ag + k0 + i * 32 * Kdim, la + i * 2048);
      gload16(bg + k0 + i * 32 * Kdim, lb + i * 2048);
    }
    __syncthreads();
#pragma unroll
    for (int kk = 0; kk < 64; kk += 32) {
      s16x8 af[4], bfr[4];
#pragma unroll
      for (int i = 0; i < 4; ++i)
        af[i] = *(const s16x8*)(As + (wr * 64 + i * 16 + c) * 64 + kk + g * 8);
#pragma unroll
      for (int i = 0; i < 4; ++i)
        bfr[i] = *(const s16x8*)(Bs + (wc * 64 + i * 16 + c) * 64 + kk + g * 8);
#pragma unroll
      for (int i = 0; i < 4; ++i)
#pragma unroll
        for (int j = 0; j < 4; ++j)
          acc[i][j] = __builtin_amdgcn_mfma_f32_16x16x32_bf16(af[i], bfr[j], acc[i][j], 0, 0, 0);
    }
    __syncthreads();
  }

  if (MODE == 1) {
    float* out = (float*)out0;
#pragma unroll
    for (int i = 0; i < 4; ++i) {
      int mb = m0 + wr * 64 + i * 16 + g * 4;
#pragma unroll
      for (int j = 0; j < 4; ++j) {
        int n = n0 + wc * 64 + j * 16 + c;
#pragma unroll
        for (int r = 0; r < 4; ++r)
          out[(size_t)(mb + r) * Ndim + n] = acc[i][j][r];
      }
    }
  } else {
    if (n0 < 1024) {               // Q part, pre-scaled for exp2-domain softmax
      const float ALPHA = 0.18033688f;  // 0.125 * log2(e)
      ushort* outQ = (ushort*)out0;
#pragma unroll
      for (int i = 0; i < 4; ++i) {
        int mb = m0 + wr * 64 + i * 16 + g * 4;
#pragma unroll
        for (int j = 0; j < 4; ++j) {
          int n = n0 + wc * 64 + j * 16 + c;
#pragma unroll
          for (int r = 0; r < 4; ++r)
            outQ[(size_t)(mb + r) * 1024 + n] = f2bf(acc[i][j][r] * ALPHA);
        }
      }
    } else if (n0 < 2048) {        // K part
#pragma unroll
      for (int i = 0; i < 4; ++i) {
        int mb = m0 + wr * 64 + i * 16 + g * 4;
#pragma unroll
        for (int j = 0; j < 4; ++j) {
          int n = n0 - 1024 + wc * 64 + j * 16 + c;
#pragma unroll
          for (int r = 0; r < 4; ++r)
            outK[(size_t)(mb + r) * 1024 + n] = f2bf(acc[i][j][r]);
        }
      }
    } else {                       // V part: write transposed per (b,h): Vt[.][s]
#pragma unroll
      for (int i = 0; i < 4; ++i) {
        int mb = m0 + wr * 64 + i * 16 + g * 4;
        int bidx = mb >> 11;       // which batch (tile never crosses the 2048 row boundary)
        int s = mb & 2047;
#pragma unroll
        for (int j = 0; j < 4; ++j) {
          int nv = n0 - 2048 + wc * 64 + j * 16 + c;
          int h = nv >> 6, d = nv & 63;
          ushort4 pk;
          pk.x = f2bf(acc[i][j][0]);
          pk.y = f2bf(acc[i][j][1]);
          pk.z = f2bf(acc[i][j][2]);
          pk.w = f2bf(acc[i][j][3]);
          *(ushort4*)(outV + ((size_t)((bidx * 16 + h) * 64 + d)) * 2048 + s) = pk;
        }
      }
    }
  }
}

// ---------------- flash causal attention (swapped QK^T, in-register softmax) --
// Flat grid 512, XCD-remapped (each XCD owns 4 heads; K/V ~2MB fits its L2).
// 4 waves x 16 q-rows; balanced chunk pairing (j, 31-j) -> 33 KV tiles/block.
// Swapped QK^T: mfma(K,Q) puts a full q-row (16 k-vals) in each lane ->
// softmax max/sum are in-register; P packed to bf16 pairs via v_cvt_pk and
// round-tripped through a tiny per-wave swizzled u32 LDS buffer (2-way free).
__global__ __launch_bounds__(256) void k_attn(const ushort* __restrict__ Qb,
                                              const ushort* __restrict__ Kb,
                                              const ushort* __restrict__ Vt,
                                              ushort* __restrict__ Yb) {
  __shared__ __align__(16) ushort Ks[2][64 * 64];
  __shared__ __align__(16) ushort Vs[2][64 * 64];
  __shared__ __align__(16) unsigned int Pp[4][16 * 32];  // per-wave packed P
  const int fid = blockIdx.x;
  const int wid = (fid & 7) * 64 + (fid >> 3);  // XCD-contiguous remap (512 = 8*64)
  const int bh = wid >> 4;                       // 0..31
  const int j = wid & 15;                        // pair index 0..15
  const int b = bh >> 4, h = bh & 15;
  const int tid = threadIdx.x, w = tid >> 6, lane = tid & 63;
  const int g = lane >> 4, c = lane & 15;
  char* pb = (char*)(&Pp[w][0]);  // this wave's P region (2 KB)

  const int trow = tid >> 3, tcol = tid & 7;
  const int csrc = tcol ^ (trow & 7);  // inverse-swizzled global source chunk
  const ushort* kgb = Kb + (size_t)(b * S_ + trow) * H_ + h * HD_ + csrc * 8;
  const ushort* vgb = Vt + (size_t)(bh * HD_ + trow) * S_ + csrc * 8;

#define STAGE(bf, tile)                                          \
  do {                                                           \
    int ks_ = (tile) * 64;                                       \
    gload16(kgb + (size_t)ks_ * H_, Ks[bf] + tid * 8);           \
    gload16(kgb + (size_t)(ks_ + 32) * H_, Ks[bf] + 2048 + tid * 8); \
    gload16(vgb + ks_, Vs[bf] + tid * 8);                        \
    gload16(vgb + ks_ + 32 * S_, Vs[bf] + 2048 + tid * 8);       \
  } while (0)

#pragma unroll 1
  for (int half = 0; half < 2; ++half) {
    const int qc = half ? (31 - j) : j;  // q-chunk index (64 rows each)
    const int q0 = qc * 64;
    const int nt = qc + 1;               // causal: KV tiles 0..qc
    const int qw = q0 + w * 16;          // wave's first q row

    // Q fragments (B-operand) in registers for the whole chunk
    s16x8 qf[2];
#pragma unroll
    for (int dc = 0; dc < 2; ++dc)
      qf[dc] = *(const s16x8*)(Qb + (size_t)(b * S_ + qw + c) * H_ +
                               h * HD_ + dc * 32 + g * 8);

    f32x4 oacc[4] = {};
    float m = -1e30f, lp = 0.f;  // per-lane: q-row = qw + c; lp = this g-group's partial sum

    // prologue: stage tile 0, drain, barrier
    STAGE(0, 0);
    asm volatile("s_waitcnt vmcnt(0)" ::: "memory");
    __builtin_amdgcn_s_barrier();
    __builtin_amdgcn_sched_barrier(0);

    int buf = 0;
#pragma unroll 1
    for (int it = 0; it < nt; ++it) {
      const int ks = it * 64;
      if (it + 1 < nt) STAGE(buf ^ 1, it + 1);  // prefetch flies under compute

      // ---- S^T = K Q^T : lane (c,g) holds S[q=qw+c][k=ks+kt*16+g*4+r] ----
      f32x4 sacc[4] = {};
      __builtin_amdgcn_s_setprio(1);
#pragma unroll
      for (int dc = 0; dc < 2; ++dc) {
#pragma unroll
        for (int kt = 0; kt < 4; ++kt) {
          int R = kt * 16 + c;
          int cc = dc * 4 + g;
          s16x8 kf = *(const s16x8*)((const char*)Ks[buf] + R * 128 + ((cc ^ (R & 7)) << 4));
          sacc[kt] = __builtin_amdgcn_mfma_f32_16x16x32_bf16(kf, qf[dc], sacc[kt], 0, 0, 0);
        }
      }
      __builtin_amdgcn_s_setprio(0);

      // ---- causal mask (only the diagonal tile) ----
      if (it == nt - 1) {
        int q = qw + c;
#pragma unroll
        for (int kt = 0; kt < 4; ++kt)
#pragma unroll
          for (int r = 0; r < 4; ++r)
            if (ks + kt * 16 + g * 4 + r > q) sacc[kt][r] = -1e30f;
      }

      // ---- row max: in-register tree + cross-g reduce ----
      float t0 = fmaxf(fmaxf(sacc[0][0], sacc[0][1]), fmaxf(sacc[0][2], sacc[0][3]));
      float t1 = fmaxf(fmaxf(sacc[1][0], sacc[1][1]), fmaxf(sacc[1][2], sacc[1][3]));
      float t2 = fmaxf(fmaxf(sacc[2][0], sacc[2][1]), fmaxf(sacc[2][2], sacc[2][3]));
      float t3 = fmaxf(fmaxf(sacc[3][0], sacc[3][1]), fmaxf(sacc[3][2], sacc[3][3]));
      float t = fmaxf(fmaxf(t0, t1), fmaxf(t2, t3));
      t = fmaxf(t, __shfl_xor(t, 16));
      t = fmaxf(t, __shfl_xor(t, 32));

      // ---- defer-max (T13): rescale only when max grew past threshold ----
      if (__any(t > m + 8.0f)) {
        float mnew = fmaxf(m, t);
        float sc = __builtin_amdgcn_exp2f(m - mnew);
        m = mnew;
        lp *= sc;
        float scq[4];
#pragma unroll
        for (int r = 0; r < 4; ++r) scq[r] = __shfl(sc, g * 4 + r);
#pragma unroll
        for (int dt = 0; dt < 4; ++dt)
#pragma unroll
          for (int r = 0; r < 4; ++r) oacc[dt][r] *= scq[r];
      }

      // ---- P = exp2(S - m); partial row sum; pack to bf16 pairs ----
      float p[4][4];
      float rs = 0.f;
#pragma unroll
      for (int kt = 0; kt < 4; ++kt)
#pragma unroll
        for (int r = 0; r < 4; ++r) {
          p[kt][r] = __builtin_amdgcn_exp2f(sacc[kt][r] - m);
          rs += p[kt][r];
        }
      lp += rs;
      unsigned int pw[8];
#pragma unroll
      for (int kt = 0; kt < 4; ++kt) {
        asm("v_cvt_pk_bf16_f32 %0, %1, %2" : "=v"(pw[kt * 2 + 0]) : "v"(p[kt][0]), "v"(p[kt][1]));
        asm("v_cvt_pk_bf16_f32 %0, %1, %2" : "=v"(pw[kt * 2 + 1]) : "v"(p[kt][2]), "v"(p[kt][3]));
      }
      // write 4x b64 to per-wave LDS, 16B-quad XOR swizzle (2-way conflict = free)
#pragma unroll
      for (int kt = 0; kt < 4; ++kt) {
        int qd = kt * 2 + (g >> 1);
        *(uint2*)(pb + c * 128 + ((qd ^ (c & 7)) << 4) + ((g & 1) << 3)) =
            make_uint2(pw[kt * 2], pw[kt * 2 + 1]);
      }
      asm volatile("s_waitcnt lgkmcnt(0)" ::: "memory");
      __builtin_amdgcn_sched_barrier(0);

      // ---- O += P V ----
      __builtin_amdgcn_s_setprio(1);
#pragma unroll
      for (int kc = 0; kc < 2; ++kc) {
        int qd = kc * 4 + g;
        s16x8 pf = *(const s16x8*)(pb + c * 128 + ((qd ^ (c & 7)) << 4));
        int cc = kc * 4 + g;
#pragma unroll
        for (int dt = 0; dt < 4; ++dt) {
          int R = dt * 16 + c;
          s16x8 vf = *(const s16x8*)((const char*)Vs[buf] + R * 128 + ((cc ^ (R & 7)) << 4));
          oacc[dt] = __builtin_amdgcn_mfma_f32_16x16x32_bf16(pf, vf, oacc[dt], 0, 0, 0);
        }
      }
      __builtin_amdgcn_s_setprio(0);

      // ---- tile boundary: prefetched loads done; all waves done reading buf ----
      asm volatile("s_waitcnt vmcnt(0)" ::: "memory");
      __builtin_amdgcn_s_barrier();
      __builtin_amdgcn_sched_barrier(0);
      buf ^= 1;
    }

    // ---- epilogue: reduce l across g, O / l -> Yb (bf16) ----
    float lt = lp;
    lt += __shfl_xor(lt, 16);
    lt += __shfl_xor(lt, 32);
    float rq[4];
#pragma unroll
    for (int r = 0; r < 4; ++r) rq[r] = 1.0f / __shfl(lt, g * 4 + r);
#pragma unroll
    for (int dt = 0; dt < 4; ++dt)
#pragma unroll
      for (int r = 0; r < 4; ++r) {
        int s = qw + g * 4 + r;
        Yb[(size_t)(b * S_ + s) * H_ + h * HD_ + dt * 16 + c] = f2bf(oacc[dt][r] * rq[r]);
      }
  }
#undef STAGE
}

extern "C" void kernel_launch(void* const* d_in, const int* in_sizes, int n_in,
                              void* d_out, int out_size, void* d_ws, size_t ws_size,
                              hipStream_t stream) {
  (void)in_sizes; (void)n_in; (void)out_size; (void)ws_size;
  const float* x = (const float*)d_in[0];
  // d_in[1] is the additive causal mask -- causality implemented directly.
  const float* Wqkv = (const float*)d_in[2];
  const float* Wout = (const float*)d_in[3];
  float* out = (float*)d_out;

  char* ws = (char*)d_ws;
  ushort* xb    = (ushort*)(ws + 0);          //  8 MB  x as bf16 [4096][1024]
  ushort* wqkvT = (ushort*)(ws + 8388608);    //  6 MB  W_qkv^T bf16 [3072][1024]
  ushort* woutT = (ushort*)(ws + 14680064);   //  2 MB  W_out^T bf16 [1024][1024]
  ushort* Qb    = (ushort*)(ws + 16777216);   //  8 MB  Q bf16 [B*S][H] (pre-scaled)
  ushort* Kb    = (ushort*)(ws + 25165824);   //  8 MB  K bf16 [B*S][H]
  ushort* Vtb   = (ushort*)(ws + 33554432);   //  8 MB  V^T bf16 [B*NH*HD][S]
  ushort* Yb    = (ushort*)(ws + 41943040);   //  8 MB  attn out bf16 [B*S][H]

  k_convert<<<dim3(4096), dim3(256), 0, stream>>>(x, xb);
  k_transpose<<<dim3(96, 32), dim3(256), 0, stream>>>(Wqkv, wqkvT, 1024, 3072);
  k_transpose<<<dim3(32, 32), dim3(256), 0, stream>>>(Wout, woutT, 1024, 1024);
  k_gemm<0><<<dim3(24, 32), dim3(256), 0, stream>>>(xb, wqkvT, (void*)Qb, Kb, Vtb, 1024, 3072);
  k_attn<<<dim3(512), dim3(256), 0, stream>>>(Qb, Kb, Vtb, Yb);
  k_gemm<1><<<dim3(8, 32), dim3(256), 0, stream>>>(Yb, woutT, (void*)out, nullptr, nullptr, 1024, 1024);
}

// Round 4
// 209.498 us; speedup vs baseline: 1.3606x; 1.0313x over previous
//
#include <hip/hip_runtime.h>

#define B_ 2
#define S_ 2048
#define H_ 1024
#define NH_ 16
#define HD_ 64

typedef short s16x8 __attribute__((ext_vector_type(8)));
typedef float f32x4 __attribute__((ext_vector_type(4)));

// float -> bf16 round-to-nearest-even (no NaN inputs here)
__device__ __forceinline__ ushort f2bf(float f) {
  union { float f; unsigned u; } v;
  v.f = f;
  unsigned r = (v.u + 0x7fffu + ((v.u >> 16) & 1u)) >> 16;
  return (ushort)r;
}

// async global->LDS, 16B per lane (dest must be wave-uniform base + lane*16)
__device__ __forceinline__ void gload16(const void* g, void* l) {
  typedef const __attribute__((address_space(1))) unsigned int* gp_t;
  typedef __attribute__((address_space(3))) unsigned int* lp_t;
  __builtin_amdgcn_global_load_lds((gp_t)g, (lp_t)l, 16, 0, 0);
}

// ------------- fused prep: x->bf16, W_qkv^T->bf16, W_out^T->bf16 -------------
// blocks [0,4096): convert x (4 floats/thread)
// blocks [4096,7168): transpose W_qkv (1024x3072 -> 3072x1024)
// blocks [7168,8192): transpose W_out (1024x1024 -> 1024x1024)
__global__ __launch_bounds__(256) void k_prep(const float* __restrict__ x,
                                              ushort* __restrict__ xb,
                                              const float* __restrict__ Wqkv,
                                              ushort* __restrict__ wqkvT,
                                              const float* __restrict__ Wout,
                                              ushort* __restrict__ woutT) {
  __shared__ ushort tile[32][33];
  const int bid = blockIdx.x;
  if (bid < 4096) {
    int i = bid * 256 + threadIdx.x;
    float4 v = ((const float4*)x)[i];
    ushort4 o;
    o.x = f2bf(v.x); o.y = f2bf(v.y); o.z = f2bf(v.z); o.w = f2bf(v.w);
    ((ushort4*)xb)[i] = o;
    return;
  }
  const float* in;
  ushort* out;
  int R = 1024, C, t;
  if (bid < 7168) { in = Wqkv; out = wqkvT; C = 3072; t = bid - 4096; }
  else            { in = Wout; out = woutT; C = 1024; t = bid - 7168; }
  int nbx = C >> 5;
  int c0 = (t % nbx) * 32, r0 = (t / nbx) * 32;
  int tr = threadIdx.x >> 5, tc = threadIdx.x & 31;
#pragma unroll
  for (int i = 0; i < 4; ++i)
    tile[tr + 8 * i][tc] = f2bf(in[(size_t)(r0 + tr + 8 * i) * C + c0 + tc]);
  __syncthreads();
#pragma unroll
  for (int i = 0; i < 4; ++i)
    out[(size_t)(c0 + tr + 8 * i) * R + r0 + tc] = tile[tc][tr + 8 * i];
}

// ---------------- GEMM: C[M][N] = A[M][K] * Bt[N][K]^T (bf16 in, f32 acc) ----
// 128x128 tile, BK=64, 2-phase double-buffered LDS pipeline (T3-min recipe):
// prologue STAGE+vmcnt(0)+barrier; loop { STAGE(next) || compute(cur);
// vmcnt(0); s_barrier }. One barrier per K-step; prefetch hides under MFMA.
// MODE 0: QKV epilogue -> Q (pre-scaled by 0.125*log2e), K row-major bf16;
//         V transposed per (b,h): Vt[(b*16+h)*64+d][s]
// MODE 1: fp32 row-major out
template <int MODE>
__global__ __launch_bounds__(256) void k_gemm(const ushort* __restrict__ A,
                                              const ushort* __restrict__ Bt,
                                              void* __restrict__ out0,
                                              ushort* __restrict__ outK,
                                              ushort* __restrict__ outV,
                                              int Kdim, int Ndim) {
  __shared__ __align__(16) ushort As[2][128 * 64];
  __shared__ __align__(16) ushort Bs[2][128 * 64];
  // bijective XCD swizzle (grid % 8 == 0 for all our launches)
  const int nwg = gridDim.x * gridDim.y;
  const int id = blockIdx.y * gridDim.x + blockIdx.x;
  const int sid = (id & 7) * (nwg >> 3) + (id >> 3);
  const int m0 = (sid / gridDim.x) * 128, n0 = (sid % gridDim.x) * 128;
  const int tid = threadIdx.x, lane = tid & 63, w = tid >> 6;
  const int g = lane >> 4, c = lane & 15;
  const int wr = w >> 1, wc = w & 1;
  f32x4 acc[4][4] = {};
  const int trow = tid >> 3, tcol = tid & 7;
  const ushort* ag = A + (size_t)(m0 + trow) * Kdim + tcol * 8;
  const ushort* bg = Bt + (size_t)(n0 + trow) * Kdim + tcol * 8;

#define STAGE_G(bf, k0)                                      \
  do {                                                       \
    _Pragma("unroll") for (int i_ = 0; i_ < 4; ++i_) {       \
      gload16(ag + (k0) + i_ * 32 * Kdim, As[bf] + tid * 8 + i_ * 2048); \
      gload16(bg + (k0) + i_ * 32 * Kdim, Bs[bf] + tid * 8 + i_ * 2048); \
    }                                                        \
  } while (0)

  const int nk = Kdim >> 6;
  STAGE_G(0, 0);
  asm volatile("s_waitcnt vmcnt(0)" ::: "memory");
  __builtin_amdgcn_s_barrier();
  __builtin_amdgcn_sched_barrier(0);

  int buf = 0;
#pragma unroll 1
  for (int t = 0; t < nk; ++t) {
    if (t + 1 < nk) STAGE_G(buf ^ 1, (t + 1) * 64);
#pragma unroll
    for (int kk = 0; kk < 64; kk += 32) {
      s16x8 af[4], bfr[4];
#pragma unroll
      for (int i = 0; i < 4; ++i)
        af[i] = *(const s16x8*)(As[buf] + (wr * 64 + i * 16 + c) * 64 + kk + g * 8);
#pragma unroll
      for (int i = 0; i < 4; ++i)
        bfr[i] = *(const s16x8*)(Bs[buf] + (wc * 64 + i * 16 + c) * 64 + kk + g * 8);
      __builtin_amdgcn_s_setprio(1);
#pragma unroll
      for (int i = 0; i < 4; ++i)
#pragma unroll
        for (int j = 0; j < 4; ++j)
          acc[i][j] = __builtin_amdgcn_mfma_f32_16x16x32_bf16(af[i], bfr[j], acc[i][j], 0, 0, 0);
      __builtin_amdgcn_s_setprio(0);
    }
    asm volatile("s_waitcnt vmcnt(0)" ::: "memory");
    __builtin_amdgcn_s_barrier();
    __builtin_amdgcn_sched_barrier(0);
    buf ^= 1;
  }
#undef STAGE_G

  if (MODE == 1) {
    float* out = (float*)out0;
#pragma unroll
    for (int i = 0; i < 4; ++i) {
      int mb = m0 + wr * 64 + i * 16 + g * 4;
#pragma unroll
      for (int j = 0; j < 4; ++j) {
        int n = n0 + wc * 64 + j * 16 + c;
#pragma unroll
        for (int r = 0; r < 4; ++r)
          out[(size_t)(mb + r) * Ndim + n] = acc[i][j][r];
      }
    }
  } else {
    if (n0 < 1024) {               // Q part, pre-scaled for exp2-domain softmax
      const float ALPHA = 0.18033688f;  // 0.125 * log2(e)
      ushort* outQ = (ushort*)out0;
#pragma unroll
      for (int i = 0; i < 4; ++i) {
        int mb = m0 + wr * 64 + i * 16 + g * 4;
#pragma unroll
        for (int j = 0; j < 4; ++j) {
          int n = n0 + wc * 64 + j * 16 + c;
#pragma unroll
          for (int r = 0; r < 4; ++r)
            outQ[(size_t)(mb + r) * 1024 + n] = f2bf(acc[i][j][r] * ALPHA);
        }
      }
    } else if (n0 < 2048) {        // K part
#pragma unroll
      for (int i = 0; i < 4; ++i) {
        int mb = m0 + wr * 64 + i * 16 + g * 4;
#pragma unroll
        for (int j = 0; j < 4; ++j) {
          int n = n0 - 1024 + wc * 64 + j * 16 + c;
#pragma unroll
          for (int r = 0; r < 4; ++r)
            outK[(size_t)(mb + r) * 1024 + n] = f2bf(acc[i][j][r]);
        }
      }
    } else {                       // V part: write transposed per (b,h): Vt[.][s]
#pragma unroll
      for (int i = 0; i < 4; ++i) {
        int mb = m0 + wr * 64 + i * 16 + g * 4;
        int bidx = mb >> 11;       // which batch (tile never crosses the 2048 row boundary)
        int s = mb & 2047;
#pragma unroll
        for (int j = 0; j < 4; ++j) {
          int nv = n0 - 2048 + wc * 64 + j * 16 + c;
          int h = nv >> 6, d = nv & 63;
          ushort4 pk;
          pk.x = f2bf(acc[i][j][0]);
          pk.y = f2bf(acc[i][j][1]);
          pk.z = f2bf(acc[i][j][2]);
          pk.w = f2bf(acc[i][j][3]);
          *(ushort4*)(outV + ((size_t)((bidx * 16 + h) * 64 + d)) * 2048 + s) = pk;
        }
      }
    }
  }
}

// ---------------- flash causal attention (swapped QK^T, in-register softmax) --
// Flat grid 512, XCD-remapped (each XCD owns 4 heads; K/V ~2MB fits its L2).
// 4 waves x 16 q-rows; balanced chunk pairing (j, 31-j) -> 33 KV tiles/block.
// Swapped QK^T: mfma(K,Q) puts a full q-row (16 k-vals) in each lane ->
// softmax max/sum are in-register; P packed to bf16 pairs via v_cvt_pk and
// round-tripped through a tiny per-wave swizzled u32 LDS buffer (2-way free).
__global__ __launch_bounds__(256) void k_attn(const ushort* __restrict__ Qb,
                                              const ushort* __restrict__ Kb,
                                              const ushort* __restrict__ Vt,
                                              ushort* __restrict__ Yb) {
  __shared__ __align__(16) ushort Ks[2][64 * 64];
  __shared__ __align__(16) ushort Vs[2][64 * 64];
  __shared__ __align__(16) unsigned int Pp[4][16 * 32];  // per-wave packed P
  const int fid = blockIdx.x;
  const int wid = (fid & 7) * 64 + (fid >> 3);  // XCD-contiguous remap (512 = 8*64)
  const int bh = wid >> 4;                       // 0..31
  const int j = wid & 15;                        // pair index 0..15
  const int b = bh >> 4, h = bh & 15;
  const int tid = threadIdx.x, w = tid >> 6, lane = tid & 63;
  const int g = lane >> 4, c = lane & 15;
  char* pb = (char*)(&Pp[w][0]);  // this wave's P region (2 KB)

  const int trow = tid >> 3, tcol = tid & 7;
  const int csrc = tcol ^ (trow & 7);  // inverse-swizzled global source chunk
  const ushort* kgb = Kb + (size_t)(b * S_ + trow) * H_ + h * HD_ + csrc * 8;
  const ushort* vgb = Vt + (size_t)(bh * HD_ + trow) * S_ + csrc * 8;

#define STAGE(bf, tile)                                          \
  do {                                                           \
    int ks_ = (tile) * 64;                                       \
    gload16(kgb + (size_t)ks_ * H_, Ks[bf] + tid * 8);           \
    gload16(kgb + (size_t)(ks_ + 32) * H_, Ks[bf] + 2048 + tid * 8); \
    gload16(vgb + ks_, Vs[bf] + tid * 8);                        \
    gload16(vgb + ks_ + 32 * S_, Vs[bf] + 2048 + tid * 8);       \
  } while (0)

#pragma unroll 1
  for (int half = 0; half < 2; ++half) {
    const int qc = half ? (31 - j) : j;  // q-chunk index (64 rows each)
    const int q0 = qc * 64;
    const int nt = qc + 1;               // causal: KV tiles 0..qc
    const int qw = q0 + w * 16;          // wave's first q row

    // Q fragments (B-operand) in registers for the whole chunk
    s16x8 qf[2];
#pragma unroll
    for (int dc = 0; dc < 2; ++dc)
      qf[dc] = *(const s16x8*)(Qb + (size_t)(b * S_ + qw + c) * H_ +
                               h * HD_ + dc * 32 + g * 8);

    f32x4 oacc[4] = {};
    float m = -1e30f, lp = 0.f;  // per-lane: q-row = qw + c; lp = this g-group's partial sum

    // prologue: stage tile 0, drain, barrier
    STAGE(0, 0);
    asm volatile("s_waitcnt vmcnt(0)" ::: "memory");
    __builtin_amdgcn_s_barrier();
    __builtin_amdgcn_sched_barrier(0);

    int buf = 0;
#pragma unroll 1
    for (int it = 0; it < nt; ++it) {
      const int ks = it * 64;
      if (it + 1 < nt) STAGE(buf ^ 1, it + 1);  // prefetch flies under compute

      // ---- S^T = K Q^T : lane (c,g) holds S[q=qw+c][k=ks+kt*16+g*4+r] ----
      f32x4 sacc[4] = {};
      __builtin_amdgcn_s_setprio(1);
#pragma unroll
      for (int dc = 0; dc < 2; ++dc) {
#pragma unroll
        for (int kt = 0; kt < 4; ++kt) {
          int R = kt * 16 + c;
          int cc = dc * 4 + g;
          s16x8 kf = *(const s16x8*)((const char*)Ks[buf] + R * 128 + ((cc ^ (R & 7)) << 4));
          sacc[kt] = __builtin_amdgcn_mfma_f32_16x16x32_bf16(kf, qf[dc], sacc[kt], 0, 0, 0);
        }
      }
      __builtin_amdgcn_s_setprio(0);

      // ---- causal mask (only the diagonal tile) ----
      if (it == nt - 1) {
        int q = qw + c;
#pragma unroll
        for (int kt = 0; kt < 4; ++kt)
#pragma unroll
          for (int r = 0; r < 4; ++r)
            if (ks + kt * 16 + g * 4 + r > q) sacc[kt][r] = -1e30f;
      }

      // ---- row max: in-register tree + cross-g reduce ----
      float t0 = fmaxf(fmaxf(sacc[0][0], sacc[0][1]), fmaxf(sacc[0][2], sacc[0][3]));
      float t1 = fmaxf(fmaxf(sacc[1][0], sacc[1][1]), fmaxf(sacc[1][2], sacc[1][3]));
      float t2 = fmaxf(fmaxf(sacc[2][0], sacc[2][1]), fmaxf(sacc[2][2], sacc[2][3]));
      float t3 = fmaxf(fmaxf(sacc[3][0], sacc[3][1]), fmaxf(sacc[3][2], sacc[3][3]));
      float t = fmaxf(fmaxf(t0, t1), fmaxf(t2, t3));
      t = fmaxf(t, __shfl_xor(t, 16));
      t = fmaxf(t, __shfl_xor(t, 32));

      // ---- defer-max (T13): rescale only when max grew past threshold ----
      if (__any(t > m + 8.0f)) {
        float mnew = fmaxf(m, t);
        float sc = __builtin_amdgcn_exp2f(m - mnew);
        m = mnew;
        lp *= sc;
        float scq[4];
#pragma unroll
        for (int r = 0; r < 4; ++r) scq[r] = __shfl(sc, g * 4 + r);
#pragma unroll
        for (int dt = 0; dt < 4; ++dt)
#pragma unroll
          for (int r = 0; r < 4; ++r) oacc[dt][r] *= scq[r];
      }

      // ---- P = exp2(S - m); partial row sum; pack to bf16 pairs ----
      float p[4][4];
      float rs = 0.f;
#pragma unroll
      for (int kt = 0; kt < 4; ++kt)
#pragma unroll
        for (int r = 0; r < 4; ++r) {
          p[kt][r] = __builtin_amdgcn_exp2f(sacc[kt][r] - m);
          rs += p[kt][r];
        }
      lp += rs;
      unsigned int pw[8];
#pragma unroll
      for (int kt = 0; kt < 4; ++kt) {
        asm("v_cvt_pk_bf16_f32 %0, %1, %2" : "=v"(pw[kt * 2 + 0]) : "v"(p[kt][0]), "v"(p[kt][1]));
        asm("v_cvt_pk_bf16_f32 %0, %1, %2" : "=v"(pw[kt * 2 + 1]) : "v"(p[kt][2]), "v"(p[kt][3]));
      }
      // write 4x b64 to per-wave LDS, 16B-quad XOR swizzle (2-way conflict = free)
#pragma unroll
      for (int kt = 0; kt < 4; ++kt) {
        int qd = kt * 2 + (g >> 1);
        *(uint2*)(pb + c * 128 + ((qd ^ (c & 7)) << 4) + ((g & 1) << 3)) =
            make_uint2(pw[kt * 2], pw[kt * 2 + 1]);
      }
      asm volatile("s_waitcnt lgkmcnt(0)" ::: "memory");
      __builtin_amdgcn_sched_barrier(0);

      // ---- O += P V ----
      __builtin_amdgcn_s_setprio(1);
#pragma unroll
      for (int kc = 0; kc < 2; ++kc) {
        int qd = kc * 4 + g;
        s16x8 pf = *(const s16x8*)(pb + c * 128 + ((qd ^ (c & 7)) << 4));
        int cc = kc * 4 + g;
#pragma unroll
        for (int dt = 0; dt < 4; ++dt) {
          int R = dt * 16 + c;
          s16x8 vf = *(const s16x8*)((const char*)Vs[buf] + R * 128 + ((cc ^ (R & 7)) << 4));
          oacc[dt] = __builtin_amdgcn_mfma_f32_16x16x32_bf16(pf, vf, oacc[dt], 0, 0, 0);
        }
      }
      __builtin_amdgcn_s_setprio(0);

      // ---- tile boundary: prefetched loads done; all waves done reading buf ----
      asm volatile("s_waitcnt vmcnt(0)" ::: "memory");
      __builtin_amdgcn_s_barrier();
      __builtin_amdgcn_sched_barrier(0);
      buf ^= 1;
    }

    // ---- epilogue: reduce l across g, O / l -> Yb (bf16) ----
    float lt = lp;
    lt += __shfl_xor(lt, 16);
    lt += __shfl_xor(lt, 32);
    float rq[4];
#pragma unroll
    for (int r = 0; r < 4; ++r) rq[r] = 1.0f / __shfl(lt, g * 4 + r);
#pragma unroll
    for (int dt = 0; dt < 4; ++dt)
#pragma unroll
      for (int r = 0; r < 4; ++r) {
        int s = qw + g * 4 + r;
        Yb[(size_t)(b * S_ + s) * H_ + h * HD_ + dt * 16 + c] = f2bf(oacc[dt][r] * rq[r]);
      }
  }
#undef STAGE
}

extern "C" void kernel_launch(void* const* d_in, const int* in_sizes, int n_in,
                              void* d_out, int out_size, void* d_ws, size_t ws_size,
                              hipStream_t stream) {
  (void)in_sizes; (void)n_in; (void)out_size; (void)ws_size;
  const float* x = (const float*)d_in[0];
  // d_in[1] is the additive causal mask -- causality implemented directly.
  const float* Wqkv = (const float*)d_in[2];
  const float* Wout = (const float*)d_in[3];
  float* out = (float*)d_out;

  char* ws = (char*)d_ws;
  ushort* xb    = (ushort*)(ws + 0);          //  8 MB  x as bf16 [4096][1024]
  ushort* wqkvT = (ushort*)(ws + 8388608);    //  6 MB  W_qkv^T bf16 [3072][1024]
  ushort* woutT = (ushort*)(ws + 14680064);   //  2 MB  W_out^T bf16 [1024][1024]
  ushort* Qb    = (ushort*)(ws + 16777216);   //  8 MB  Q bf16 [B*S][H] (pre-scaled)
  ushort* Kb    = (ushort*)(ws + 25165824);   //  8 MB  K bf16 [B*S][H]
  ushort* Vtb   = (ushort*)(ws + 33554432);   //  8 MB  V^T bf16 [B*NH*HD][S]
  ushort* Yb    = (ushort*)(ws + 41943040);   //  8 MB  attn out bf16 [B*S][H]

  k_prep<<<dim3(8192), dim3(256), 0, stream>>>(x, xb, Wqkv, wqkvT, Wout, woutT);
  k_gemm<0><<<dim3(24, 32), dim3(256), 0, stream>>>(xb, wqkvT, (void*)Qb, Kb, Vtb, 1024, 3072);
  k_attn<<<dim3(512), dim3(256), 0, stream>>>(Qb, Kb, Vtb, Yb);
  k_gemm<1><<<dim3(8, 32), dim3(256), 0, stream>>>(Yb, woutT, (void*)out, nullptr, nullptr, 1024, 1024);
}